// Round 19
// baseline (312.929 us; speedup 1.0000x reference)
//
#include <hip/hip_runtime.h>
#include <hip/hip_bf16.h>
#include <math.h>

// ---------------------------------------------------------------------------
// MoE gate via fp16 hi/lo split MFMA, 3 products (validated round 5):
//   x = xh + xl/2048,  W*64 = wh + wl/2048
//   logit = ( xh·wh + (xh·wl + xl·wh)/2048 ) / 64
// Round 19 = round 18 (119.5us, best) + split-K semaphore routing fusion:
//   each bm group's LAST-arriving GEMM block (device atomicAdd on cnt[bm],
//   __threadfence release) routes its 128 tokens in the epilogue (8 waves
//   x 16 tokens, r5-validated wave routing, fp64 combine of KS partials).
//   Separate routing dispatch + launch gap eliminated; routing overlaps
//   straggler GEMM blocks. cnt[] zeroed per-launch in convert_w.
// GEMM body / schedule / layouts / numerics identical to r18 (passed).
// ---------------------------------------------------------------------------

typedef _Float16 f16x8 __attribute__((ext_vector_type(8)));
typedef float    f32x4 __attribute__((ext_vector_type(4)));

__device__ __forceinline__ void glds16(const void* g, void* l) {
  __builtin_amdgcn_global_load_lds(
      (const __attribute__((address_space(1))) void*)g,
      (__attribute__((address_space(3))) void*)l, 16, 0, 0);
}

__device__ __forceinline__ unsigned short f2h(float f) {
  _Float16 h = (_Float16)f;                       // v_cvt_f16_f32, RTN
  return __builtin_bit_cast(unsigned short, h);
}
__device__ __forceinline__ float h2f(unsigned short b) {
  return (float)__builtin_bit_cast(_Float16, b);
}

// swizzle: 64B rows, 4 granules of 16B; bijective in gi per row.
__device__ __forceinline__ int swz(int gi, int row) {
  return gi ^ (row & 3) ^ ((row >> 2) & 3);
}

// ---------------------------------------------------------------------------
// W [256][7168] fp32 -> Whi/Wlo fp16, 256-row pre-swizzled K-tiles (BK=32):
// K-tile t in 0..223 = 256 rows x 32 f16 = 8192 ushorts (16KB).
// element (r,k): gi=k>>3, addr = t*8192 + r*32 + swz(gi,r)*8 + (k&7).
// Whi = fp16(64*W); Wlo = fp16((64*W - Whi) * 2048).   (validated r9/r16)
// Also zeroes the split-K semaphores (blocks 0/1, threads 224..255).
// ---------------------------------------------------------------------------
__global__ __launch_bounds__(256) void convert_w(
    const float* __restrict__ W,
    unsigned short* __restrict__ Whi, unsigned short* __restrict__ Wlo,
    int* __restrict__ cnt)
{
  const int e = blockIdx.x;           // expert/row 0..255
  const int t = threadIdx.x;          // 0..255, use 224 (one K-tile each)
  if (t >= 224) {
    const int idx = e * 32 + (t - 224);
    if (e < 2) cnt[idx] = 0;          // 64 semaphores
    return;
  }
  const float* src = W + (size_t)e * 7168 + t * 32;
  const size_t tbase = (size_t)t * 8192 + (size_t)e * 32;
  #pragma unroll
  for (int g = 0; g < 4; ++g) {       // granule gi = g, k = g*8..g*8+7
    unsigned int hw[4], lw[4];
    #pragma unroll
    for (int p = 0; p < 4; ++p) {
      float f0 = src[g * 8 + 2 * p] * 64.0f;
      float f1 = src[g * 8 + 2 * p + 1] * 64.0f;
      unsigned short h0 = f2h(f0), h1 = f2h(f1);
      unsigned short l0 = f2h((f0 - h2f(h0)) * 2048.0f);
      unsigned short l1 = f2h((f1 - h2f(h1)) * 2048.0f);
      hw[p] = (unsigned)h0 | ((unsigned)h1 << 16);
      lw[p] = (unsigned)l0 | ((unsigned)l1 << 16);
    }
    const size_t base = tbase + (size_t)(swz(g, e) * 8);
    *(uint4*)(Whi + base) = make_uint4(hw[0], hw[1], hw[2], hw[3]);
    *(uint4*)(Wlo + base) = make_uint4(lw[0], lw[1], lw[2], lw[3]);
  }
}

// ---------------------------------------------------------------------------
// GEMM + fused routing: BM=128, BN=256, BK=32, K-split KS. 512 threads =
// 8 waves (2Mx4N), wave tile 64x64 = 4x4 frags of 16x16x32 f16 MFMA,
// 3 products. TRIPLE-buffered LDS (3 x 48KB). Per tile s:
//   1. issue glds B(s+2) -> buf[(s+2)%3]
//   2. issue A(s+2) loads (clamped)
//   3. compute buf[s%3] (setprio)
//   4. convert pa(s+1) -> ds_write A -> buf[(s+1)%3]
//   5. vmcnt(6) + lgkmcnt(0) + s_barrier
// Epilogue: write Spart partial; threadfence + atomicAdd(cnt[bm]); the
// last of the KS blocks routes its 128 tokens (8 waves x 16 tokens).
// Grid 1-D: ks = bid % KS (XCD-affine), bm = bid / KS.
// ---------------------------------------------------------------------------
#define BUF_SZ   49152
#define O_ALO    8192
#define O_BH     16384
#define O_BL     32768

__global__ __launch_bounds__(512, 2) void gate_gemm(
    const float* __restrict__ X,
    const unsigned short* __restrict__ Whi,
    const unsigned short* __restrict__ Wlo,
    float* __restrict__ Spart, int D, int TILES, int KS,
    const float* __restrict__ bias,
    float* __restrict__ outw, float* __restrict__ outi,
    int* __restrict__ cnt, int T)
{
  __shared__ char lds[147456];   // 3 buffers
  __shared__ int done_s;

  const int bid = blockIdx.x;
  const int ks = bid % KS;                 // XCD-affine
  const int bm = bid / KS;
  const int tid = threadIdx.x, lane = tid & 63, wid = tid >> 6;
  const int wm = wid >> 2, wn = wid & 3;   // 2M x 4N wave grid
  const int TM = bm * 128;
  const int k0base = ks * TILES * 32;      // K-chunk start

  // A staging: 4 threads per row, 8 contiguous fp32 each (one granule)
  const int srow = tid >> 2, sg = tid & 3;
  const float* xsrc = X + (size_t)(TM + srow) * D + k0base + sg * 8;
  const int aw = srow * 64 + swz(sg, srow) * 16;   // byte offset

  const unsigned short* wh_tile = Whi + (size_t)(ks * TILES) * 8192;
  const unsigned short* wl_tile = Wlo + (size_t)(ks * TILES) * 8192;

  f32x4 acc1[4][4], acc2[4][4];
  #pragma unroll
  for (int m = 0; m < 4; ++m)
    #pragma unroll
    for (int n = 0; n < 4; ++n) { acc1[m][n] = (f32x4)0.0f; acc2[m][n] = (f32x4)0.0f; }

  // fragment read byte offsets, fixed per lane
  int aro[4], bro[4];
  const int gi = lane >> 4;
  #pragma unroll
  for (int m = 0; m < 4; ++m) {
    const int row = wm * 64 + m * 16 + (lane & 15);
    aro[m] = row * 64 + swz(gi, row) * 16;
  }
  #pragma unroll
  for (int n = 0; n < 4; ++n) {
    const int row = wn * 64 + n * 16 + (lane & 15);
    bro[n] = row * 64 + swz(gi, row) * 16;
  }

  // ---- prologue: A(0) loads first, stage B(0)->buf0, B(1)->buf1,
  //      A(0) convert+write, prefetch pa(1) ----
  float4 pa0, pa1, pb0, pb1;
  {
    float4 a0 = *(const float4*)(xsrc);          // oldest in queue
    float4 a1 = *(const float4*)(xsrc + 4);
    #pragma unroll
    for (int i = 0; i < 2; ++i) {                // glds B(0) (4/wave)
      const int c = wid * 2 + i;                 // chunk 0..15, wave-uniform
      glds16(wh_tile + c * 512 + lane * 8, lds + O_BH + c * 1024);
      glds16(wl_tile + c * 512 + lane * 8, lds + O_BL + c * 1024);
    }
    if (TILES > 1) {                             // glds B(1) (4/wave)
      #pragma unroll
      for (int i = 0; i < 2; ++i) {
        const int c = wid * 2 + i;
        glds16(wh_tile + 8192 + c * 512 + lane * 8, lds + BUF_SZ + O_BH + c * 1024);
        glds16(wl_tile + 8192 + c * 512 + lane * 8, lds + BUF_SZ + O_BL + c * 1024);
      }
    }
    __builtin_amdgcn_sched_barrier(0);
    // prefetch pa(1) (newest)
    const int s1 = (TILES > 1) ? 1 : 0;
    pa0 = *(const float4*)(xsrc + (size_t)s1 * 32);
    pa1 = *(const float4*)(xsrc + (size_t)s1 * 32 + 4);
    __builtin_amdgcn_sched_barrier(0);
    // convert + write A(0) into buf0 (compiler waits a0/a1 here)
    float ff[8] = {a0.x, a0.y, a0.z, a0.w, a1.x, a1.y, a1.z, a1.w};
    unsigned int hw[4], lw[4];
    #pragma unroll
    for (int q = 0; q < 4; ++q) {
      float f0 = ff[2 * q], f1 = ff[2 * q + 1];
      unsigned short h0 = f2h(f0), h1 = f2h(f1);
      unsigned short l0 = f2h((f0 - h2f(h0)) * 2048.0f);
      unsigned short l1 = f2h((f1 - h2f(h1)) * 2048.0f);
      hw[q] = (unsigned)h0 | ((unsigned)h1 << 16);
      lw[q] = (unsigned)l0 | ((unsigned)l1 << 16);
    }
    *(uint4*)(lds + aw)         = make_uint4(hw[0], hw[1], hw[2], hw[3]);
    *(uint4*)(lds + O_ALO + aw) = make_uint4(lw[0], lw[1], lw[2], lw[3]);
    __builtin_amdgcn_sched_barrier(0);
  }
  // B(0) done: after-glds(0) items = glds(1) 4 + pa(1) 2 = 6
  asm volatile("s_waitcnt vmcnt(6) lgkmcnt(0)" ::: "memory");
  __builtin_amdgcn_sched_barrier(0);
  __builtin_amdgcn_s_barrier();

  for (int s = 0; s < TILES; ++s) {
    char* base_c  = lds + (s % 3) * BUF_SZ;
    char* base_n1 = lds + ((s + 1) % 3) * BUF_SZ;
    char* base_n2 = lds + ((s + 2) % 3) * BUF_SZ;

    // 1. issue glds B(s+2), two tiles ahead (oldest vmem this tile)
    if (s + 2 < TILES) {
      const unsigned short* wh = wh_tile + (size_t)(s + 2) * 8192;
      const unsigned short* wl = wl_tile + (size_t)(s + 2) * 8192;
      #pragma unroll
      for (int i = 0; i < 2; ++i) {
        const int c = wid * 2 + i;
        glds16(wh + c * 512 + lane * 8, base_n2 + O_BH + c * 1024);
        glds16(wl + c * 512 + lane * 8, base_n2 + O_BL + c * 1024);
      }
    }
    __builtin_amdgcn_sched_barrier(0);

    // 2. issue A(s+2) loads (clamped)
    {
      int sn = s + 2; if (sn > TILES - 1) sn = TILES - 1;
      pb0 = *(const float4*)(xsrc + (size_t)sn * 32);
      pb1 = *(const float4*)(xsrc + (size_t)sn * 32 + 4);
    }
    __builtin_amdgcn_sched_barrier(0);

    // 3. compute from buf[s%3]
    {
      const char* Ahi = base_c;         const char* Alo = base_c + O_ALO;
      const char* Bh  = base_c + O_BH;  const char* Bl  = base_c + O_BL;
      f16x8 ah[4], al[4], bh[4], bl[4];
      #pragma unroll
      for (int m = 0; m < 4; ++m) {
        ah[m] = *(const f16x8*)(Ahi + aro[m]);
        al[m] = *(const f16x8*)(Alo + aro[m]);
      }
      #pragma unroll
      for (int n = 0; n < 4; ++n) {
        bh[n] = *(const f16x8*)(Bh + bro[n]);
        bl[n] = *(const f16x8*)(Bl + bro[n]);
      }
      __builtin_amdgcn_s_setprio(1);
      #pragma unroll
      for (int m = 0; m < 4; ++m)
        #pragma unroll
        for (int n = 0; n < 4; ++n) {
          acc1[m][n] = __builtin_amdgcn_mfma_f32_16x16x32_f16(ah[m], bh[n], acc1[m][n], 0, 0, 0);
          acc2[m][n] = __builtin_amdgcn_mfma_f32_16x16x32_f16(ah[m], bl[n], acc2[m][n], 0, 0, 0);
          acc2[m][n] = __builtin_amdgcn_mfma_f32_16x16x32_f16(al[m], bh[n], acc2[m][n], 0, 0, 0);
        }
      __builtin_amdgcn_s_setprio(0);
    }

    // 4. convert + ds_write A(s+1) into buf[(s+1)%3]
    if (s + 1 < TILES) {
      float ff[8] = {pa0.x, pa0.y, pa0.z, pa0.w, pa1.x, pa1.y, pa1.z, pa1.w};
      unsigned int hw[4], lw[4];
      #pragma unroll
      for (int q = 0; q < 4; ++q) {
        float f0 = ff[2 * q], f1 = ff[2 * q + 1];
        unsigned short h0 = f2h(f0), h1 = f2h(f1);
        unsigned short l0 = f2h((f0 - h2f(h0)) * 2048.0f);
        unsigned short l1 = f2h((f1 - h2f(h1)) * 2048.0f);
        hw[q] = (unsigned)h0 | ((unsigned)h1 << 16);
        lw[q] = (unsigned)l0 | ((unsigned)l1 << 16);
      }
      *(uint4*)(base_n1 + aw)         = make_uint4(hw[0], hw[1], hw[2], hw[3]);
      *(uint4*)(base_n1 + O_ALO + aw) = make_uint4(lw[0], lw[1], lw[2], lw[3]);
    }
    pa0 = pb0; pa1 = pb1;

    // 5. counted drain + barrier: glds(s+1)/pa(s+1) done; glds(s+2) 4 +
    //    pa(s+2) 2 stay in flight.
    asm volatile("s_waitcnt vmcnt(6) lgkmcnt(0)" ::: "memory");
    __builtin_amdgcn_sched_barrier(0);
    __builtin_amdgcn_s_barrier();
  }

  // epilogue: logit partial = (acc1 + acc2/2048) / 64
  // C/D layout: col=lane&15, row=(lane>>4)*4+reg
  float* Sp = Spart + (size_t)ks * T * 256;
  #pragma unroll
  for (int m = 0; m < 4; ++m)
    #pragma unroll
    for (int n = 0; n < 4; ++n)
      #pragma unroll
      for (int r = 0; r < 4; ++r) {
        const int t = TM + wm * 64 + m * 16 + (lane >> 4) * 4 + r;
        const int e = wn * 64 + n * 16 + (lane & 15);
        Sp[(size_t)t * 256 + e] =
            (acc1[m][n][r] + acc2[m][n][r] * (1.0f / 2048.0f)) * (1.0f / 64.0f);
      }

  // ---- split-K semaphore: last block of this bm group routes its tokens --
  __threadfence();                     // device-scope release of Spart writes
  if (tid == 0) done_s = atomicAdd(&cnt[bm], 1);
  __syncthreads();
  if (done_s != KS - 1) return;
  __threadfence();                     // acquire side

  // route 128 tokens: 8 waves x 16 tokens (r5-validated wave routing)
  for (int i = 0; i < 16; ++i) {
    const int t = TM + wid * 16 + i;

    double l[4] = {0.0, 0.0, 0.0, 0.0};
    for (int k = 0; k < KS; ++k) {
      float4 p = *(const float4*)(Spart + (size_t)k * T * 256
                                  + (size_t)t * 256 + lane * 4);
      l[0] += (double)p.x; l[1] += (double)p.y;
      l[2] += (double)p.z; l[3] += (double)p.w;
    }

    float4 bi = *(const float4*)(bias + lane * 4);
    float orig[4], s[4];
    #pragma unroll
    for (int u = 0; u < 4; ++u)
      orig[u] = 1.0f / (1.0f + expf(-(float)l[u]));
    s[0] = orig[0] + bi.x; s[1] = orig[1] + bi.y;
    s[2] = orig[2] + bi.z; s[3] = orig[3] + bi.w;

    // per-lane top-2 of its 4 biased scores
    float m1 = -INFINITY, m2 = -INFINITY;
    #pragma unroll
    for (int u = 0; u < 4; ++u) {
      float v = s[u];
      if (v > m1) { m2 = m1; m1 = v; }
      else if (v > m2) { m2 = v; }
    }
    // merge top-2 across the 8 lanes of the group
    #pragma unroll
    for (int off = 1; off < 8; off <<= 1) {
      float o1 = __shfl_xor(m1, off, 64);
      float o2 = __shfl_xor(m2, off, 64);
      if (o1 > m1) { m2 = fmaxf(m1, o2); m1 = o1; }
      else         { m2 = fmaxf(m2, o1); }
    }
    const float gscore = m1 + m2;

    const int g = lane >> 3;
    int rank = 0;
    #pragma unroll
    for (int j = 0; j < 8; ++j) {
      float gs = __shfl(gscore, j * 8, 64);
      rank += (gs > gscore || (gs == gscore && j < g)) ? 1 : 0;
    }
    if (rank >= 4) { s[0] = s[1] = s[2] = s[3] = -INFINITY; }

    float wsum = 0.0f, sel_w = 0.0f;
    int sel_i = 0;
    #pragma unroll
    for (int it = 0; it < 8; ++it) {
      float bv = s[0]; int bu = 0;
      #pragma unroll
      for (int u = 1; u < 4; ++u)
        if (s[u] > bv) { bv = s[u]; bu = u; }
      float v = bv;
      int ix = lane * 4 + bu;
      float og = orig[bu];
      #pragma unroll
      for (int off = 1; off < 64; off <<= 1) {
        float ov  = __shfl_xor(v,  off, 64);
        int   oix = __shfl_xor(ix, off, 64);
        float oog = __shfl_xor(og, off, 64);
        if (ov > v || (ov == v && oix < ix)) { v = ov; ix = oix; og = oog; }
      }
      if (lane == it) { sel_w = og; sel_i = ix; }
      wsum += og;
      if ((ix >> 2) == lane) s[ix & 3] = -INFINITY;
    }

    if (lane < 8) {
      outw[(size_t)t * 8 + lane] = sel_w / wsum * 2.5f;
      outi[(size_t)t * 8 + lane] = (float)sel_i;
    }
  }
}

extern "C" void kernel_launch(void* const* d_in, const int* in_sizes, int n_in,
                              void* d_out, int out_size, void* d_ws, size_t ws_size,
                              hipStream_t stream) {
  const float* x = (const float*)d_in[0];
  const float* w = (const float*)d_in[1];
  const float* b = (const float*)d_in[2];
  const int E = in_sizes[2];                  // 256
  const int D = in_sizes[1] / E;              // 7168
  const int T = in_sizes[0] / D;              // 8192

  unsigned short* Whi = (unsigned short*)d_ws;                       // 3.67 MB
  unsigned short* Wlo = (unsigned short*)((char*)d_ws + (4u << 20)); // 3.67 MB
  float* Spart = (float*)((char*)d_ws + (8u << 20));                 // KS x 8 MB

  // K-split 4 (validated r18); semaphores after Spart
  const size_t per_part = (size_t)T * E * 4;
  const int KS = 4;
  const int TILES = D / (32 * KS);            // 56
  int* cnt = (int*)((char*)d_ws + (8u << 20) + (size_t)KS * per_part);

  float* outw = (float*)d_out;
  float* outi = outw + (size_t)T * 8;

  convert_w<<<E, 256, 0, stream>>>(w, Whi, Wlo, cnt);
  // 1-D grid, ks fastest (XCD-affine): KS*(T/128) = 256 blocks
  gate_gemm<<<KS * (T / 128), 512, 0, stream>>>(
      x, Whi, Wlo, Spart, D, TILES, KS, b, outw, outi, cnt, T);
}

// Round 21
// 120.947 us; speedup vs baseline: 2.5873x; 2.5873x over previous
//
#include <hip/hip_runtime.h>
#include <hip/hip_bf16.h>
#include <math.h>

// ---------------------------------------------------------------------------
// MoE gate via fp16 hi/lo split MFMA, 3 products (validated round 5):
//   x = xh + xl/2048,  W*64 = wh + wl/2048
//   logit = ( xh·wh + (xh·wl + xl·wh)/2048 ) / 64
// Round 21 = round 18 (119.5us) with the RACE FIX: tile-end wait changed
// vmcnt(6) -> vmcnt(2), so ALL glds are drained before every s_barrier
// (r18/r20 left 4 glds in flight across the barrier; identical source
// passed once and failed post-timing once -> timing-dependent race on
// LDS staging visibility). The only loads now crossing barriers are the
// 2 pure-register A-prefetch loads (compiler-tracked, safe). glds(s+2)
// still overlaps its whole issuing tile (~1400cyc >> L2 latency), so
// the fix is ~zero-cost.
// Structure: BM=128, BN=256, BK=32, KS=4; 512 thr / 8 waves (2Mx4N),
// wave tile 64x64; TRIPLE-buffered LDS (3x48KB), glds issued 2 tiles
// ahead; XCD-affine ks decode; separate fp64-combine routing kernel.
// ---------------------------------------------------------------------------

typedef _Float16 f16x8 __attribute__((ext_vector_type(8)));
typedef float    f32x4 __attribute__((ext_vector_type(4)));

__device__ __forceinline__ void glds16(const void* g, void* l) {
  __builtin_amdgcn_global_load_lds(
      (const __attribute__((address_space(1))) void*)g,
      (__attribute__((address_space(3))) void*)l, 16, 0, 0);
}

__device__ __forceinline__ unsigned short f2h(float f) {
  _Float16 h = (_Float16)f;                       // v_cvt_f16_f32, RTN
  return __builtin_bit_cast(unsigned short, h);
}
__device__ __forceinline__ float h2f(unsigned short b) {
  return (float)__builtin_bit_cast(_Float16, b);
}

// swizzle: 64B rows, 4 granules of 16B; bijective in gi per row.
__device__ __forceinline__ int swz(int gi, int row) {
  return gi ^ (row & 3) ^ ((row >> 2) & 3);
}

// ---------------------------------------------------------------------------
// W [256][7168] fp32 -> Whi/Wlo fp16, 256-row pre-swizzled K-tiles (BK=32):
// K-tile t in 0..223 = 256 rows x 32 f16 = 8192 ushorts (16KB).
// element (r,k): gi=k>>3, addr = t*8192 + r*32 + swz(gi,r)*8 + (k&7).
// Whi = fp16(64*W); Wlo = fp16((64*W - Whi) * 2048).   (validated r9/r16)
// ---------------------------------------------------------------------------
__global__ __launch_bounds__(256) void convert_w(
    const float* __restrict__ W,
    unsigned short* __restrict__ Whi, unsigned short* __restrict__ Wlo)
{
  const int e = blockIdx.x;           // expert/row 0..255
  const int t = threadIdx.x;          // 0..255, use 224 (one K-tile each)
  if (t >= 224) return;
  const float* src = W + (size_t)e * 7168 + t * 32;
  const size_t tbase = (size_t)t * 8192 + (size_t)e * 32;
  #pragma unroll
  for (int g = 0; g < 4; ++g) {       // granule gi = g, k = g*8..g*8+7
    unsigned int hw[4], lw[4];
    #pragma unroll
    for (int p = 0; p < 4; ++p) {
      float f0 = src[g * 8 + 2 * p] * 64.0f;
      float f1 = src[g * 8 + 2 * p + 1] * 64.0f;
      unsigned short h0 = f2h(f0), h1 = f2h(f1);
      unsigned short l0 = f2h((f0 - h2f(h0)) * 2048.0f);
      unsigned short l1 = f2h((f1 - h2f(h1)) * 2048.0f);
      hw[p] = (unsigned)h0 | ((unsigned)h1 << 16);
      lw[p] = (unsigned)l0 | ((unsigned)l1 << 16);
    }
    const size_t base = tbase + (size_t)(swz(g, e) * 8);
    *(uint4*)(Whi + base) = make_uint4(hw[0], hw[1], hw[2], hw[3]);
    *(uint4*)(Wlo + base) = make_uint4(lw[0], lw[1], lw[2], lw[3]);
  }
}

// ---------------------------------------------------------------------------
// GEMM: BM=128, BN=256, BK=32, K-split KS. 512 threads = 8 waves (2Mx4N),
// wave tile 64x64 = 4x4 frags of 16x16x32 f16 MFMA, 3 products.
// TRIPLE-buffered LDS (3 x 48KB = 144KB). Per tile s:
//   1. issue glds B(s+2) -> buf[(s+2)%3]   (4 glds/wave, 2 tiles ahead)
//   2. issue A(s+2) loads (2/thread, clamped)
//   3. compute buf[s%3] (setprio)
//   4. convert pa(s+1) -> ds_write A -> buf[(s+1)%3]
//   5. vmcnt(2) + lgkmcnt(0) + s_barrier   (ALL glds drained; only the 2
//      pa register loads stay in flight -- race-safe)
// Grid 1-D: ks = bid % KS (XCD-affine), bm = bid / KS.
// ---------------------------------------------------------------------------
#define BUF_SZ   49152
#define O_ALO    8192
#define O_BH     16384
#define O_BL     32768

__global__ __launch_bounds__(512, 2) void gate_gemm(
    const float* __restrict__ X,
    const unsigned short* __restrict__ Whi,
    const unsigned short* __restrict__ Wlo,
    float* __restrict__ Spart, int D, int TILES, int KS)
{
  __shared__ char lds[147456];   // 3 buffers

  const int bid = blockIdx.x;
  const int ks = bid % KS;                 // XCD-affine
  const int bm = bid / KS;
  const int tid = threadIdx.x, lane = tid & 63, wid = tid >> 6;
  const int wm = wid >> 2, wn = wid & 3;   // 2M x 4N wave grid
  const int TM = bm * 128;
  const int k0base = ks * TILES * 32;      // K-chunk start

  // A staging: 4 threads per row, 8 contiguous fp32 each (one granule)
  const int srow = tid >> 2, sg = tid & 3;
  const float* xsrc = X + (size_t)(TM + srow) * D + k0base + sg * 8;
  const int aw = srow * 64 + swz(sg, srow) * 16;   // byte offset

  const unsigned short* wh_tile = Whi + (size_t)(ks * TILES) * 8192;
  const unsigned short* wl_tile = Wlo + (size_t)(ks * TILES) * 8192;

  f32x4 acc1[4][4], acc2[4][4];
  #pragma unroll
  for (int m = 0; m < 4; ++m)
    #pragma unroll
    for (int n = 0; n < 4; ++n) { acc1[m][n] = (f32x4)0.0f; acc2[m][n] = (f32x4)0.0f; }

  // fragment read byte offsets, fixed per lane
  int aro[4], bro[4];
  const int gi = lane >> 4;
  #pragma unroll
  for (int m = 0; m < 4; ++m) {
    const int row = wm * 64 + m * 16 + (lane & 15);
    aro[m] = row * 64 + swz(gi, row) * 16;
  }
  #pragma unroll
  for (int n = 0; n < 4; ++n) {
    const int row = wn * 64 + n * 16 + (lane & 15);
    bro[n] = row * 64 + swz(gi, row) * 16;
  }

  // ---- prologue: A(0) loads first, stage B(0)->buf0, B(1)->buf1,
  //      A(0) convert+write, prefetch pa(1) ----
  float4 pa0, pa1, pb0, pb1;
  {
    float4 a0 = *(const float4*)(xsrc);          // oldest in queue
    float4 a1 = *(const float4*)(xsrc + 4);
    #pragma unroll
    for (int i = 0; i < 2; ++i) {                // glds B(0) (4/wave)
      const int c = wid * 2 + i;                 // chunk 0..15, wave-uniform
      glds16(wh_tile + c * 512 + lane * 8, lds + O_BH + c * 1024);
      glds16(wl_tile + c * 512 + lane * 8, lds + O_BL + c * 1024);
    }
    if (TILES > 1) {                             // glds B(1) (4/wave)
      #pragma unroll
      for (int i = 0; i < 2; ++i) {
        const int c = wid * 2 + i;
        glds16(wh_tile + 8192 + c * 512 + lane * 8, lds + BUF_SZ + O_BH + c * 1024);
        glds16(wl_tile + 8192 + c * 512 + lane * 8, lds + BUF_SZ + O_BL + c * 1024);
      }
    }
    __builtin_amdgcn_sched_barrier(0);
    // prefetch pa(1) (newest)
    const int s1 = (TILES > 1) ? 1 : 0;
    pa0 = *(const float4*)(xsrc + (size_t)s1 * 32);
    pa1 = *(const float4*)(xsrc + (size_t)s1 * 32 + 4);
    __builtin_amdgcn_sched_barrier(0);
    // convert + write A(0) into buf0 (compiler waits a0/a1 here)
    float ff[8] = {a0.x, a0.y, a0.z, a0.w, a1.x, a1.y, a1.z, a1.w};
    unsigned int hw[4], lw[4];
    #pragma unroll
    for (int q = 0; q < 4; ++q) {
      float f0 = ff[2 * q], f1 = ff[2 * q + 1];
      unsigned short h0 = f2h(f0), h1 = f2h(f1);
      unsigned short l0 = f2h((f0 - h2f(h0)) * 2048.0f);
      unsigned short l1 = f2h((f1 - h2f(h1)) * 2048.0f);
      hw[q] = (unsigned)h0 | ((unsigned)h1 << 16);
      lw[q] = (unsigned)l0 | ((unsigned)l1 << 16);
    }
    *(uint4*)(lds + aw)         = make_uint4(hw[0], hw[1], hw[2], hw[3]);
    *(uint4*)(lds + O_ALO + aw) = make_uint4(lw[0], lw[1], lw[2], lw[3]);
    __builtin_amdgcn_sched_barrier(0);
  }
  // drain ALL glds (B(0) and B(1)); only pa(1) register loads stay in flight
  asm volatile("s_waitcnt vmcnt(2) lgkmcnt(0)" ::: "memory");
  __builtin_amdgcn_sched_barrier(0);
  __builtin_amdgcn_s_barrier();

  for (int s = 0; s < TILES; ++s) {
    char* base_c  = lds + (s % 3) * BUF_SZ;
    char* base_n1 = lds + ((s + 1) % 3) * BUF_SZ;
    char* base_n2 = lds + ((s + 2) % 3) * BUF_SZ;

    // 1. issue glds B(s+2), two tiles ahead (oldest vmem this tile)
    if (s + 2 < TILES) {
      const unsigned short* wh = wh_tile + (size_t)(s + 2) * 8192;
      const unsigned short* wl = wl_tile + (size_t)(s + 2) * 8192;
      #pragma unroll
      for (int i = 0; i < 2; ++i) {
        const int c = wid * 2 + i;
        glds16(wh + c * 512 + lane * 8, base_n2 + O_BH + c * 1024);
        glds16(wl + c * 512 + lane * 8, base_n2 + O_BL + c * 1024);
      }
    }
    __builtin_amdgcn_sched_barrier(0);

    // 2. issue A(s+2) loads (clamped)
    {
      int sn = s + 2; if (sn > TILES - 1) sn = TILES - 1;
      pb0 = *(const float4*)(xsrc + (size_t)sn * 32);
      pb1 = *(const float4*)(xsrc + (size_t)sn * 32 + 4);
    }
    __builtin_amdgcn_sched_barrier(0);

    // 3. compute from buf[s%3]
    {
      const char* Ahi = base_c;         const char* Alo = base_c + O_ALO;
      const char* Bh  = base_c + O_BH;  const char* Bl  = base_c + O_BL;
      f16x8 ah[4], al[4], bh[4], bl[4];
      #pragma unroll
      for (int m = 0; m < 4; ++m) {
        ah[m] = *(const f16x8*)(Ahi + aro[m]);
        al[m] = *(const f16x8*)(Alo + aro[m]);
      }
      #pragma unroll
      for (int n = 0; n < 4; ++n) {
        bh[n] = *(const f16x8*)(Bh + bro[n]);
        bl[n] = *(const f16x8*)(Bl + bro[n]);
      }
      __builtin_amdgcn_s_setprio(1);
      #pragma unroll
      for (int m = 0; m < 4; ++m)
        #pragma unroll
        for (int n = 0; n < 4; ++n) {
          acc1[m][n] = __builtin_amdgcn_mfma_f32_16x16x32_f16(ah[m], bh[n], acc1[m][n], 0, 0, 0);
          acc2[m][n] = __builtin_amdgcn_mfma_f32_16x16x32_f16(ah[m], bl[n], acc2[m][n], 0, 0, 0);
          acc2[m][n] = __builtin_amdgcn_mfma_f32_16x16x32_f16(al[m], bh[n], acc2[m][n], 0, 0, 0);
        }
      __builtin_amdgcn_s_setprio(0);
    }

    // 4. convert + ds_write A(s+1) into buf[(s+1)%3]
    if (s + 1 < TILES) {
      float ff[8] = {pa0.x, pa0.y, pa0.z, pa0.w, pa1.x, pa1.y, pa1.z, pa1.w};
      unsigned int hw[4], lw[4];
      #pragma unroll
      for (int q = 0; q < 4; ++q) {
        float f0 = ff[2 * q], f1 = ff[2 * q + 1];
        unsigned short h0 = f2h(f0), h1 = f2h(f1);
        unsigned short l0 = f2h((f0 - h2f(h0)) * 2048.0f);
        unsigned short l1 = f2h((f1 - h2f(h1)) * 2048.0f);
        hw[q] = (unsigned)h0 | ((unsigned)h1 << 16);
        lw[q] = (unsigned)l0 | ((unsigned)l1 << 16);
      }
      *(uint4*)(base_n1 + aw)         = make_uint4(hw[0], hw[1], hw[2], hw[3]);
      *(uint4*)(base_n1 + O_ALO + aw) = make_uint4(lw[0], lw[1], lw[2], lw[3]);
    }
    pa0 = pb0; pa1 = pb1;

    // 5. drain ALL glds before the barrier (race fix); only the 2 pa(s+2)
    //    register loads stay in flight across it.
    asm volatile("s_waitcnt vmcnt(2) lgkmcnt(0)" ::: "memory");
    __builtin_amdgcn_sched_barrier(0);
    __builtin_amdgcn_s_barrier();
  }

  // epilogue: logit partial = (acc1 + acc2/2048) / 64
  // C/D layout: col=lane&15, row=(lane>>4)*4+reg
  float* Sp = Spart + (size_t)ks * 8192 * 256;
  #pragma unroll
  for (int m = 0; m < 4; ++m)
    #pragma unroll
    for (int n = 0; n < 4; ++n)
      #pragma unroll
      for (int r = 0; r < 4; ++r) {
        const int t = TM + wm * 64 + m * 16 + (lane >> 4) * 4 + r;
        const int e = wn * 64 + n * 16 + (lane & 15);
        Sp[(size_t)t * 256 + e] =
            (acc1[m][n][r] + acc2[m][n][r] * (1.0f / 2048.0f)) * (1.0f / 64.0f);
      }
}

// ---------------------------------------------------------------------------
// Routing: one wave per token. logit = sum of KS fp32 partials in DOUBLE
// (exact); scores = sigmoid (fp32); then grouped top-k (8 groups, top-2
// group score, top-4 groups, top-8 experts, renorm * 2.5).
// ---------------------------------------------------------------------------
__global__ __launch_bounds__(256) void gate_routing(
    const float* __restrict__ Spart, int KS,
    const float* __restrict__ bias,
    float* __restrict__ outw, float* __restrict__ outi, int T)
{
  const int lane = threadIdx.x & 63;
  const int wave = threadIdx.x >> 6;
  const int t = blockIdx.x * 4 + wave;
  if (t >= T) return;

  double l[4] = {0.0, 0.0, 0.0, 0.0};
  for (int ks = 0; ks < KS; ++ks) {
    float4 p = *(const float4*)(Spart + (size_t)ks * T * 256
                                + (size_t)t * 256 + lane * 4);
    l[0] += (double)p.x; l[1] += (double)p.y;
    l[2] += (double)p.z; l[3] += (double)p.w;
  }

  float4 bi = *(const float4*)(bias + lane * 4);
  float orig[4], s[4];
  #pragma unroll
  for (int u = 0; u < 4; ++u)
    orig[u] = 1.0f / (1.0f + expf(-(float)l[u]));
  s[0] = orig[0] + bi.x; s[1] = orig[1] + bi.y;
  s[2] = orig[2] + bi.z; s[3] = orig[3] + bi.w;

  // per-lane top-2 of its 4 biased scores
  float m1 = -INFINITY, m2 = -INFINITY;
  #pragma unroll
  for (int u = 0; u < 4; ++u) {
    float v = s[u];
    if (v > m1) { m2 = m1; m1 = v; }
    else if (v > m2) { m2 = v; }
  }
  // merge top-2 across the 8 lanes of the group
  #pragma unroll
  for (int off = 1; off < 8; off <<= 1) {
    float o1 = __shfl_xor(m1, off, 64);
    float o2 = __shfl_xor(m2, off, 64);
    if (o1 > m1) { m2 = fmaxf(m1, o2); m1 = o1; }
    else         { m2 = fmaxf(m2, o1); }
  }
  const float gscore = m1 + m2;

  const int g = lane >> 3;
  int rank = 0;
  #pragma unroll
  for (int j = 0; j < 8; ++j) {
    float gs = __shfl(gscore, j * 8, 64);
    rank += (gs > gscore || (gs == gscore && j < g)) ? 1 : 0;
  }
  if (rank >= 4) { s[0] = s[1] = s[2] = s[3] = -INFINITY; }

  float wsum = 0.0f, sel_w = 0.0f;
  int sel_i = 0;
  #pragma unroll
  for (int it = 0; it < 8; ++it) {
    float bv = s[0]; int bu = 0;
    #pragma unroll
    for (int u = 1; u < 4; ++u)
      if (s[u] > bv) { bv = s[u]; bu = u; }
    float v = bv;
    int ix = lane * 4 + bu;
    float og = orig[bu];
    #pragma unroll
    for (int off = 1; off < 64; off <<= 1) {
      float ov  = __shfl_xor(v,  off, 64);
      int   oix = __shfl_xor(ix, off, 64);
      float oog = __shfl_xor(og, off, 64);
      if (ov > v || (ov == v && oix < ix)) { v = ov; ix = oix; og = oog; }
    }
    if (lane == it) { sel_w = og; sel_i = ix; }
    wsum += og;
    if ((ix >> 2) == lane) s[ix & 3] = -INFINITY;
  }

  if (lane < 8) {
    outw[(size_t)t * 8 + lane] = sel_w / wsum * 2.5f;
    outi[(size_t)t * 8 + lane] = (float)sel_i;
  }
}

extern "C" void kernel_launch(void* const* d_in, const int* in_sizes, int n_in,
                              void* d_out, int out_size, void* d_ws, size_t ws_size,
                              hipStream_t stream) {
  const float* x = (const float*)d_in[0];
  const float* w = (const float*)d_in[1];
  const float* b = (const float*)d_in[2];
  const int E = in_sizes[2];                  // 256
  const int D = in_sizes[1] / E;              // 7168
  const int T = in_sizes[0] / D;              // 8192

  unsigned short* Whi = (unsigned short*)d_ws;                       // 3.67 MB
  unsigned short* Wlo = (unsigned short*)((char*)d_ws + (4u << 20)); // 3.67 MB
  float* Spart = (float*)((char*)d_ws + (8u << 20));                 // KS x 8 MB

  // K-split 4 (halved Spart traffic vs 8; chain 56 within noise budget)
  const size_t per_part = (size_t)T * E * 4;
  int KS = 2;
  if (ws_size >= (8u << 20) + 4 * per_part) KS = 4;
  const int TILES = D / (32 * KS);            // 56 for KS=4

  float* outw = (float*)d_out;
  float* outi = outw + (size_t)T * 8;

  convert_w<<<E, 256, 0, stream>>>(w, Whi, Wlo);
  // 1-D grid, ks fastest (XCD-affine): KS*(T/128) = 256 blocks at KS=4
  gate_gemm<<<KS * (T / 128), 512, 0, stream>>>(x, Whi, Wlo, Spart, D, TILES, KS);
  gate_routing<<<(T + 3) / 4, 256, 0, stream>>>(Spart, KS, b, outw, outi, T);
}